// Round 8
// baseline (144520.605 us; speedup 1.0000x reference)
//
#include <hip/hip_runtime.h>
#include <math.h>

// NSE recurrent model, B=32, L=1024, K=256.
// Step t: reader LSTM -> hr_t ; scores s_l = hr_t . mem_l ; softmax z ;
// m_rt = sum z_l mem_l ; writer gates = [hr,m_rt]@Wf + hw@wWh + bf  (composer folded:
// Wf = cW@wWx, bf = cb@wWx + wb) ; mem update deferred to next step's attn pass.
//
// R8: ONE kernel launch per step. Roles by blockIdx:
//   [0,1024)    attn chunks (b,c) -> partials, then flag++ (per batch-group)
//   [1024,1152) reader t+1, BG=4 batched (independent of this step's attn/writer)
//   [1152,1280) writer, BG=4 batched; spins on flags[bg] (attn of its 4 batches done)
// Deadlock-free: attn blocks have lowest indices and never wait -> always drain.

#define Bb 32
#define LL 1024
#define KK 256
#define N4K 1024
#define N2K 512
#define NC 32      // L-chunks per batch row (attn)
#define RC 32      // rows per chunk
#define BG 4       // batches per GEMV block
#define BK 8192    // Bb*KK

__device__ __forceinline__ float sigf(float v) { return 1.0f / (1.0f + __expf(-v)); }

// ---------------- init: mem <- x, zero states + flags ----------------
__global__ void k_init(const float* __restrict__ x, float* __restrict__ mem,
                       float* __restrict__ states, unsigned* __restrict__ flags) {
    long long n = (long long)Bb * LL * KK;
    for (long long i = (long long)blockIdx.x * blockDim.x + threadIdx.x; i < n;
         i += (long long)gridDim.x * blockDim.x)
        mem[i] = x[i];
    for (int i = blockIdx.x * blockDim.x + threadIdx.x; i < 8 * Bb * KK;
         i += gridDim.x * blockDim.x)
        states[i] = 0.0f;
    if (blockIdx.x == 0 && threadIdx.x < 16) flags[threadIdx.x] = 0u;
}

// ---------------- pre: Wf = cW @ wWx (512x1024), bf = cb @ wWx + wb ----------------
__global__ __launch_bounds__(256) void k_pre(
    const float* __restrict__ cW, const float* __restrict__ cb,
    const float* __restrict__ wWx, const float* __restrict__ wb,
    float* __restrict__ Wf, float* __restrict__ bf) {
    int tid = threadIdx.x;
    __shared__ float srow[N2K];
    if (blockIdx.x < N2K) {
        int kr = blockIdx.x;
        srow[tid] = cW[(size_t)kr * N2K + tid];
        srow[KK + tid] = cW[(size_t)kr * N2K + KK + tid];
        __syncthreads();
#pragma unroll
        for (int rep = 0; rep < 4; rep++) {
            int col = rep * 256 + tid;
            float a = 0.f;
#pragma unroll 4
            for (int c = 0; c < N2K; c++) a += srow[c] * wWx[(size_t)c * N4K + col];
            Wf[(size_t)kr * N4K + col] = a;
        }
    } else {
        int col = (blockIdx.x - N2K) * 256 + tid;
        float a = wb[col];
#pragma unroll 4
        for (int c = 0; c < N2K; c++) a += cb[c] * wWx[(size_t)c * N4K + col];
        bf[col] = a;
    }
}

// ---------------- batched reader (BG=4): (bg, jg) -> 16 j x 4 gates, 4-way k-split ----
__device__ __forceinline__ void reader4(
    int bg, int jg, int tid, int t1,
    const float* __restrict__ x, const float* __restrict__ rWx,
    const float* __restrict__ rWh, const float* __restrict__ rbv,
    const float* __restrict__ hr_in, const float* __restrict__ cr_in,
    float* __restrict__ hr_out, float* __restrict__ cr_out, float* sm) {
    float* shin = sm;          // 4*512
    float* sred = sm + 2048;   // 1024
    float* sg   = sm + 3072;   // 256
#pragma unroll
    for (int b = 0; b < BG; b++) {
        int bglob = bg * BG + b;
        shin[b * N2K + tid] = x[((size_t)bglob * LL + t1) * KK + tid];
        shin[b * N2K + KK + tid] = hr_in[bglob * KK + tid];
    }
    __syncthreads();
    int c64 = tid & 63, ks = tid >> 6;
    int g = c64 >> 4, jq = c64 & 15;
    int col = g * KK + jg * 16 + jq;
    float acc[BG];
    float binit = (ks == 0) ? rbv[col] : 0.f;
#pragma unroll
    for (int b = 0; b < BG; b++) acc[b] = binit;
    int k0 = ks * 128;
    const float* W = (ks < 2) ? (rWx + (size_t)k0 * N4K + col)
                              : (rWh + (size_t)(k0 - KK) * N4K + col);
    for (int kk = 0; kk < 128; kk += 4) {
        float w0 = W[(size_t)(kk + 0) * N4K];
        float w1 = W[(size_t)(kk + 1) * N4K];
        float w2 = W[(size_t)(kk + 2) * N4K];
        float w3 = W[(size_t)(kk + 3) * N4K];
#pragma unroll
        for (int b = 0; b < BG; b++) {
            float4 v = *(const float4*)&shin[b * N2K + k0 + kk];
            acc[b] += w0 * v.x + w1 * v.y + w2 * v.z + w3 * v.w;
        }
    }
#pragma unroll
    for (int b = 0; b < BG; b++) sred[(ks * 64 + c64) * BG + b] = acc[b];
    __syncthreads();
    {
        int cc = tid >> 2, b = tid & 3;
        sg[tid] = sred[(0 * 64 + cc) * BG + b] + sred[(1 * 64 + cc) * BG + b] +
                  sred[(2 * 64 + cc) * BG + b] + sred[(3 * 64 + cc) * BG + b];
    }
    __syncthreads();
    if (tid < 16 * BG) {
        int jl = tid >> 2, b = tid & 3;
        int bglob = bg * BG + b;
        int j = jg * 16 + jl;
        float gi = sg[(0 * 16 + jl) * BG + b], gf = sg[(1 * 16 + jl) * BG + b];
        float gG = sg[(2 * 16 + jl) * BG + b], go = sg[(3 * 16 + jl) * BG + b];
        float cn = sigf(gf) * cr_in[bglob * KK + j] + sigf(gi) * tanhf(gG);
        float hn = sigf(go) * tanhf(cn);
        cr_out[bglob * KK + j] = cn;
        hr_out[bglob * KK + j] = hn;
    }
}

__global__ __launch_bounds__(256) void k_rd0(
    const float* __restrict__ x, const float* __restrict__ rWx,
    const float* __restrict__ rWh, const float* __restrict__ rbv,
    const float* __restrict__ hr_in, const float* __restrict__ cr_in,
    float* __restrict__ hr_out, float* __restrict__ cr_out) {
    __shared__ float sm[3328];
    reader4(blockIdx.x >> 4, blockIdx.x & 15, threadIdx.x, 0, x, rWx, rWh, rbv,
            hr_in, cr_in, hr_out, cr_out, sm);
}

// ---------------- fused per-step kernel ----------------
__global__ __launch_bounds__(256) void k_step(
    const float* __restrict__ x, const float* __restrict__ rWx,
    const float* __restrict__ rWh, const float* __restrict__ rbv,
    const float* __restrict__ wWh, float* __restrict__ out,
    float* __restrict__ ws, int t, int do_reader) {
    float* mem   = ws;
    float* st    = ws + (size_t)Bb * LL * KK;
    float* s_    = st + 8 * BK;
    float* partM = s_ + Bb * LL;
    float* partS = partM + Bb * NC;
    float* partV = partS + Bb * NC;
    float* Mf    = partV + (size_t)Bb * NC * KK;
    float* Sf    = Mf + Bb;
    float* Wf    = Sf + Bb;
    float* bf    = Wf + (size_t)N2K * N4K;
    unsigned* flags = (unsigned*)(bf + N4K);

    int pi = t & 1, po = (t + 1) & 1;
    float* hr[2] = {st + 0 * BK, st + 1 * BK};
    float* cr[2] = {st + 2 * BK, st + 3 * BK};
    float* hw[2] = {st + 4 * BK, st + 5 * BK};
    float* cw[2] = {st + 6 * BK, st + 7 * BK};

    __shared__ float sm[4800];
    int tid = threadIdx.x;
    int blk = blockIdx.x;

    if (blk < 1024) {
        // ================= attn role: chunk (b,c) =================
        int b = blk >> 5, c = blk & 31;
        int w = tid >> 6, ln = tid & 63;
        float* sV = sm;            // 4*256
        float* sM4 = sm + 1024;    // 4
        float* sS4 = sm + 1028;    // 4
        const float* hrp = hr[po];
        const float* hwp = hw[pi];
        float4 h4 = ((const float4*)(hrp + b * KK))[ln];
        float4 w4 = make_float4(0.f, 0.f, 0.f, 0.f);
        float Mprev = 0.f, invS = 0.f;
        int upd = (t > 0);
        if (upd) {
            w4 = ((const float4*)(hwp + b * KK))[ln];
            Mprev = Mf[b];
            invS = 1.0f / Sf[b];
        }
        float Mw = -INFINITY, Sw = 0.f;
        float4 Vw = make_float4(0.f, 0.f, 0.f, 0.f);
        int l0 = c * RC + w * 8;
#pragma unroll
        for (int i = 0; i < 8; i++) {
            int l = l0 + i;
            float4* vp = (float4*)(mem + ((size_t)(b * LL + l)) * KK) + ln;
            float4 v = *vp;
            if (upd) {
                float z = __expf(s_[b * LL + l] - Mprev) * invS;
                float om = 1.0f - z;
                v.x = v.x * om + w4.x * z;
                v.y = v.y * om + w4.y * z;
                v.z = v.z * om + w4.z * z;
                v.w = v.w * om + w4.w * z;
                *vp = v;
            }
            float d = h4.x * v.x + h4.y * v.y + h4.z * v.z + h4.w * v.w;
#pragma unroll
            for (int m = 1; m < 64; m <<= 1) d += __shfl_xor(d, m, 64);
            if (ln == 0) s_[b * LL + l] = d;
            float nM = fmaxf(Mw, d);
            float sc = __expf(Mw - nM);
            float e = __expf(d - nM);
            Sw = Sw * sc + e;
            Vw.x = Vw.x * sc + e * v.x;
            Vw.y = Vw.y * sc + e * v.y;
            Vw.z = Vw.z * sc + e * v.z;
            Vw.w = Vw.w * sc + e * v.w;
            Mw = nM;
        }
        sV[w * KK + ln * 4 + 0] = Vw.x;
        sV[w * KK + ln * 4 + 1] = Vw.y;
        sV[w * KK + ln * 4 + 2] = Vw.z;
        sV[w * KK + ln * 4 + 3] = Vw.w;
        if (ln == 0) { sM4[w] = Mw; sS4[w] = Sw; }
        __syncthreads();
        float M = fmaxf(fmaxf(sM4[0], sM4[1]), fmaxf(sM4[2], sM4[3]));
        float e0 = __expf(sM4[0] - M), e1 = __expf(sM4[1] - M);
        float e2 = __expf(sM4[2] - M), e3 = __expf(sM4[3] - M);
        float S = e0 * sS4[0] + e1 * sS4[1] + e2 * sS4[2] + e3 * sS4[3];
        float V = e0 * sV[0 * KK + tid] + e1 * sV[1 * KK + tid] +
                  e2 * sV[2 * KK + tid] + e3 * sV[3 * KK + tid];
        partV[((size_t)(b * NC + c)) * KK + tid] = V;
        if (tid == 0) {
            partM[b * NC + c] = M;
            partS[b * NC + c] = S;
        }
        __syncthreads();
        if (tid == 0) {
            __threadfence_system();
            __hip_atomic_fetch_add(&flags[b >> 2], 1u, __ATOMIC_RELEASE,
                                   __HIP_MEMORY_SCOPE_SYSTEM);
        }
    } else if (blk < 1152) {
        // ================= reader role (t+1), BG=4 =================
        if (!do_reader) return;
        int r2 = blk - 1024;
        reader4(r2 >> 4, r2 & 15, tid, t + 1, x, rWx, rWh, rbv,
                hr[po], cr[po], hr[pi], cr[pi], sm);
    } else {
        // ================= writer role, BG=4 =================
        int r2 = blk - 1152;
        int bg = r2 >> 4, jg = r2 & 15;
        float* shin = sm;            // 4*768
        float* sred = sm + 3072;     // 1024
        float* sg   = sm + 4096;     // 256
        float* sMp  = sm + 4352;     // 128
        float* sSp  = sm + 4480;     // 128
        float* sEp  = sm + 4608;     // 128
        float* sMS  = sm + 4736;     // 4
        float* sSS  = sm + 4740;     // 4
        if (tid == 0) {
            unsigned tgt = 128u * (unsigned)(t + 1);
            while (__hip_atomic_load(&flags[bg], __ATOMIC_ACQUIRE,
                                     __HIP_MEMORY_SCOPE_SYSTEM) < tgt)
                __builtin_amdgcn_s_sleep(8);
        }
        __syncthreads();
        // softmax partial reduce for 4 batches
        if (tid < 128) {
            int bl = tid >> 5, c = tid & 31;
            sMp[tid] = partM[(bg * BG + bl) * NC + c];
            sSp[tid] = partS[(bg * BG + bl) * NC + c];
        }
        __syncthreads();
        if (tid < BG) {
            float M = -INFINITY;
#pragma unroll
            for (int c = 0; c < NC; c++) M = fmaxf(M, sMp[tid * NC + c]);
            sMS[tid] = M;
        }
        __syncthreads();
        if (tid < 128) sEp[tid] = __expf(sMp[tid] - sMS[tid >> 5]);
        __syncthreads();
        if (tid < BG) {
            float S = 0.f;
#pragma unroll
            for (int c = 0; c < NC; c++) S += sEp[tid * NC + c] * sSp[tid * NC + c];
            sSS[tid] = S;
            if (jg == 0) { Mf[bg * BG + tid] = sMS[tid]; Sf[bg * BG + tid] = S; }
        }
        __syncthreads();
        const float* hrp = hr[po];
        const float* hwp = hw[pi];
#pragma unroll
        for (int b = 0; b < BG; b++) {
            int bglob = bg * BG + b;
            float V = 0.f;
            for (int c = 0; c < NC; c++)
                V += sEp[b * NC + c] * partV[((size_t)(bglob * NC + c)) * KK + tid];
            shin[b * 768 + KK + tid] = V / sSS[b];
            shin[b * 768 + tid] = hrp[bglob * KK + tid];
            shin[b * 768 + N2K + tid] = hwp[bglob * KK + tid];
        }
        __syncthreads();
        // batched GEMV: 64 cols x 4 k-splits over 768 rows
        int c64 = tid & 63, ks = tid >> 6;
        int g = c64 >> 4, jq = c64 & 15;
        int col = g * KK + jg * 16 + jq;
        float acc[BG];
        float binit = (ks == 0) ? bf[col] : 0.f;
#pragma unroll
        for (int b = 0; b < BG; b++) acc[b] = binit;
        int k0 = ks * 192, k1 = k0 + 192;
        int kb = k1 < N2K ? k1 : N2K;
        for (int k = k0; k < kb; k += 4) {
            float w0 = Wf[(size_t)(k + 0) * N4K + col];
            float w1 = Wf[(size_t)(k + 1) * N4K + col];
            float w2 = Wf[(size_t)(k + 2) * N4K + col];
            float w3 = Wf[(size_t)(k + 3) * N4K + col];
#pragma unroll
            for (int b = 0; b < BG; b++) {
                float4 v = *(const float4*)&shin[b * 768 + k];
                acc[b] += w0 * v.x + w1 * v.y + w2 * v.z + w3 * v.w;
            }
        }
        for (int k = (k0 > N2K ? k0 : N2K); k < k1; k += 4) {
            float w0 = wWh[(size_t)(k - N2K + 0) * N4K + col];
            float w1 = wWh[(size_t)(k - N2K + 1) * N4K + col];
            float w2 = wWh[(size_t)(k - N2K + 2) * N4K + col];
            float w3 = wWh[(size_t)(k - N2K + 3) * N4K + col];
#pragma unroll
            for (int b = 0; b < BG; b++) {
                float4 v = *(const float4*)&shin[b * 768 + k];
                acc[b] += w0 * v.x + w1 * v.y + w2 * v.z + w3 * v.w;
            }
        }
#pragma unroll
        for (int b = 0; b < BG; b++) sred[(ks * 64 + c64) * BG + b] = acc[b];
        __syncthreads();
        {
            int cc = tid >> 2, b = tid & 3;
            sg[tid] = sred[(0 * 64 + cc) * BG + b] + sred[(1 * 64 + cc) * BG + b] +
                      sred[(2 * 64 + cc) * BG + b] + sred[(3 * 64 + cc) * BG + b];
        }
        __syncthreads();
        if (tid < 16 * BG) {
            int jl = tid >> 2, b = tid & 3;
            int bglob = bg * BG + b;
            int j = jg * 16 + jl;
            float gi = sg[(0 * 16 + jl) * BG + b], gf = sg[(1 * 16 + jl) * BG + b];
            float gG = sg[(2 * 16 + jl) * BG + b], go = sg[(3 * 16 + jl) * BG + b];
            float cn = sigf(gf) * cw[pi][bglob * KK + j] + sigf(gi) * tanhf(gG);
            float hn = sigf(go) * tanhf(cn);
            cw[po][bglob * KK + j] = cn;
            hw[po][bglob * KK + j] = hn;
            out[((size_t)bglob * LL + t) * KK + j] = hn;
        }
    }
}

// ---------------- host ----------------
extern "C" void kernel_launch(void* const* d_in, const int* in_sizes, int n_in,
                              void* d_out, int out_size, void* d_ws, size_t ws_size,
                              hipStream_t stream) {
    const float* x   = (const float*)d_in[0];
    const float* rWx = (const float*)d_in[1];
    const float* rWh = (const float*)d_in[2];
    const float* rb  = (const float*)d_in[3];
    const float* wWx = (const float*)d_in[4];
    const float* wWh = (const float*)d_in[5];
    const float* wb  = (const float*)d_in[6];
    const float* cW  = (const float*)d_in[7];
    const float* cb  = (const float*)d_in[8];
    float* out = (float*)d_out;

    float* ws = (float*)d_ws;
    const size_t MEM = (size_t)Bb * LL * KK;
    float* mem = ws;
    float* states = ws + MEM;
    float* hr1 = states + 1 * Bb * KK;
    float* cr1 = states + 3 * Bb * KK;
    float* s_  = states + 8 * Bb * KK;
    float* partM = s_ + (size_t)Bb * LL;
    float* partS = partM + Bb * NC;
    float* partV = partS + Bb * NC;
    float* Mf    = partV + (size_t)Bb * NC * KK;
    float* Sf    = Mf + Bb;
    float* Wf    = Sf + Bb;
    float* bf    = Wf + (size_t)N2K * N4K;
    unsigned* flags = (unsigned*)(bf + N4K);

    k_init<<<4096, 256, 0, stream>>>(x, mem, states, flags);
    k_pre<<<516, 256, 0, stream>>>(cW, cb, wWx, wb, Wf, bf);
    // reader t=0: hr(0),cr(0)=zeros (states[0],[2]) -> writes hr[1],cr[1] (parity for t=0: po=1)
    k_rd0<<<128, 256, 0, stream>>>(x, rWx, rWh, rb, states, states + 2 * Bb * KK, hr1, cr1);

    for (int t = 0; t < LL; t++) {
        k_step<<<1280, 256, 0, stream>>>(x, rWx, rWh, rb, wWh, out, ws, t,
                                         (t + 1 < LL) ? 1 : 0);
    }
}

// Round 10
// 35622.787 us; speedup vs baseline: 4.0570x; 4.0570x over previous
//
#include <hip/hip_runtime.h>
#include <math.h>

// NSE recurrent model, B=32, L=1024, K=256.
// Step t: reader LSTM -> hr_t ; scores s_l = hr_t . mem_l ; softmax z ;
// m_rt = sum z_l mem_l ; writer gates = [hr,m_rt]@Wf + hw@wWh + bf  (composer folded:
// Wf = cW@wWx, bf = cb@wWx + wb) ; mem update deferred to next step's attn pass.
//
// R10 = R5 champion (fp32 everywhere) + two changes:
//  (1) BG=2 batched writer/reader GEMVs: weights read once per 2 batches
//      (k_wrf traffic 176 -> ~96 MB/step), k_wrf grid 512 blocks (2/CU).
//  (2) k_attn: skip mem update+store when z <= 1e-7 (softmax is sharply peaked;
//      worst-case drift ~4e-4 over 1024 steps), preload s[] off the dep chain.

#define Bb 32
#define LL 1024
#define KK 256
#define N4K 1024   // 4*K
#define N2K 512    // 2*K
#define NC 32      // L-chunks per batch row in attention kernel
#define RC 32      // rows per chunk = LL/NC
#define ZEPS 1e-7f

__device__ __forceinline__ float sigf(float v) { return 1.0f / (1.0f + __expf(-v)); }

// ---------------- init: mem <- x, zero LSTM states ----------------
__global__ void k_init(const float* __restrict__ x, float* __restrict__ mem,
                       float* __restrict__ states /* 8 * B*K floats */) {
    long long n = (long long)Bb * LL * KK;
    for (long long i = (long long)blockIdx.x * blockDim.x + threadIdx.x; i < n;
         i += (long long)gridDim.x * blockDim.x)
        mem[i] = x[i];
    for (int i = blockIdx.x * blockDim.x + threadIdx.x; i < 8 * Bb * KK;
         i += gridDim.x * blockDim.x)
        states[i] = 0.0f;
}

// ---------------- pre: Wf = cW @ wWx (512x1024), bf = cb @ wWx + wb ----------------
__global__ __launch_bounds__(256) void k_pre(
    const float* __restrict__ cW, const float* __restrict__ cb,
    const float* __restrict__ wWx, const float* __restrict__ wb,
    float* __restrict__ Wf, float* __restrict__ bf) {
    int tid = threadIdx.x;
    __shared__ float srow[N2K];
    if (blockIdx.x < N2K) {
        int kr = blockIdx.x;
        srow[tid] = cW[(size_t)kr * N2K + tid];
        srow[KK + tid] = cW[(size_t)kr * N2K + KK + tid];
        __syncthreads();
#pragma unroll
        for (int rep = 0; rep < 4; rep++) {
            int col = rep * 256 + tid;
            float a = 0.f;
#pragma unroll 4
            for (int c = 0; c < N2K; c++) a += srow[c] * wWx[(size_t)c * N4K + col];
            Wf[(size_t)kr * N4K + col] = a;
        }
    } else {
        int col = (blockIdx.x - N2K) * 256 + tid;
        float a = wb[col];
#pragma unroll 4
        for (int c = 0; c < N2K; c++) a += cb[c] * wWx[(size_t)c * N4K + col];
        bf[col] = a;
    }
}

// ---------------- BG=2 reader LSTM: (bg, jg) -> 16 j x 4 gates, 4-way k-split ------
// shin layout: [b][512] = [x(256) | hr(256)] for b in {0,1}
__device__ __forceinline__ void reader2(
    int bg, int jg, int tid, int t1,
    const float* __restrict__ x, const float* __restrict__ rWx,
    const float* __restrict__ rWh, const float* __restrict__ rbv,
    const float* __restrict__ hr_in, const float* __restrict__ cr_in,
    float* __restrict__ hr_out, float* __restrict__ cr_out,
    float* shin /*1024*/, float* sred /*512*/, float* sg /*128*/) {
#pragma unroll
    for (int b = 0; b < 2; b++) {
        int bglob = bg * 2 + b;
        shin[b * N2K + tid] = x[((size_t)bglob * LL + t1) * KK + tid];
        shin[b * N2K + KK + tid] = hr_in[bglob * KK + tid];
    }
    __syncthreads();
    int c64 = tid & 63, ks = tid >> 6;
    int g = c64 >> 4, jq = c64 & 15;
    int col = g * KK + jg * 16 + jq;
    float binit = (ks == 0) ? rbv[col] : 0.f;
    float acc0 = binit, acc1 = binit;
    int k0 = ks * 128;
    const float* W = (ks < 2) ? (rWx + (size_t)k0 * N4K + col)
                              : (rWh + (size_t)(k0 - KK) * N4K + col);
    for (int kk = 0; kk < 128; kk += 4) {
        float w0 = W[(size_t)(kk + 0) * N4K];
        float w1 = W[(size_t)(kk + 1) * N4K];
        float w2 = W[(size_t)(kk + 2) * N4K];
        float w3 = W[(size_t)(kk + 3) * N4K];
        float4 va = *(const float4*)&shin[k0 + kk];
        float4 vb = *(const float4*)&shin[N2K + k0 + kk];
        acc0 += w0 * va.x + w1 * va.y + w2 * va.z + w3 * va.w;
        acc1 += w0 * vb.x + w1 * vb.y + w2 * vb.z + w3 * vb.w;
    }
    sred[(ks * 64 + c64) * 2 + 0] = acc0;
    sred[(ks * 64 + c64) * 2 + 1] = acc1;
    __syncthreads();
    if (tid < 128) {
        int cc = tid >> 1, b = tid & 1;
        sg[tid] = sred[(0 * 64 + cc) * 2 + b] + sred[(1 * 64 + cc) * 2 + b] +
                  sred[(2 * 64 + cc) * 2 + b] + sred[(3 * 64 + cc) * 2 + b];
    }
    __syncthreads();
    if (tid < 32) {
        int jl = tid >> 1, b = tid & 1;
        int bglob = bg * 2 + b;
        int j = jg * 16 + jl;
        float gi = sg[(0 * 16 + jl) * 2 + b], gf = sg[(1 * 16 + jl) * 2 + b];
        float gG = sg[(2 * 16 + jl) * 2 + b], go = sg[(3 * 16 + jl) * 2 + b];
        float cn = sigf(gf) * cr_in[bglob * KK + j] + sigf(gi) * tanhf(gG);
        float hn = sigf(go) * tanhf(cn);
        cr_out[bglob * KK + j] = cn;
        hr_out[bglob * KK + j] = hn;
    }
}

__global__ __launch_bounds__(256) void k_rd(
    const float* __restrict__ x, const float* __restrict__ rWx,
    const float* __restrict__ rWh, const float* __restrict__ rbv,
    const float* __restrict__ hr_in, const float* __restrict__ cr_in,
    float* __restrict__ hr_out, float* __restrict__ cr_out, int t) {
    __shared__ float shin[1024];
    __shared__ float sred[512];
    __shared__ float sg[128];
    reader2(blockIdx.x >> 4, blockIdx.x & 15, threadIdx.x, t, x, rWx, rWh, rbv,
            hr_in, cr_in, hr_out, cr_out, shin, sred, sg);
}

// ---------------- attention: (deferred mem update) + scores + online softmax ----------------
// grid (NC, B), 256 threads = 4 waves; wave handles 8 rows; lane holds K-slice [ln*4, ln*4+4)
__global__ __launch_bounds__(256) void k_attn(
    float* __restrict__ mem, const float* __restrict__ hr,
    float* __restrict__ s, float* __restrict__ partM, float* __restrict__ partS,
    float* __restrict__ partV, const float* __restrict__ hw_prev,
    const float* __restrict__ Mf, const float* __restrict__ Sf, int upd) {
    int c = blockIdx.x, b = blockIdx.y;
    int tid = threadIdx.x, w = tid >> 6, ln = tid & 63;
    int l0 = c * RC + w * 8;

    float4 h4 = ((const float4*)(hr + b * KK))[ln];
    float4 w4 = make_float4(0.f, 0.f, 0.f, 0.f);
    float Mprev = 0.f, invS = 0.f;
    float sv[8];
    if (upd) {
        w4 = ((const float4*)(hw_prev + b * KK))[ln];
        Mprev = Mf[b];
        invS = 1.0f / Sf[b];
#pragma unroll
        for (int i = 0; i < 8; i++) sv[i] = s[b * LL + l0 + i];
    }

    float Mw = -INFINITY, Sw = 0.f;
    float4 Vw = make_float4(0.f, 0.f, 0.f, 0.f);
#pragma unroll
    for (int i = 0; i < 8; i++) {
        int l = l0 + i;
        float4* vp = (float4*)(mem + ((size_t)(b * LL + l)) * KK) + ln;
        float4 v = *vp;
        if (upd) {
            float z = __expf(sv[i] - Mprev) * invS;
            if (z > ZEPS) {
                float om = 1.0f - z;
                v.x = v.x * om + w4.x * z;
                v.y = v.y * om + w4.y * z;
                v.z = v.z * om + w4.z * z;
                v.w = v.w * om + w4.w * z;
                *vp = v;
            }
        }
        float d = h4.x * v.x + h4.y * v.y + h4.z * v.z + h4.w * v.w;
#pragma unroll
        for (int m = 1; m < 64; m <<= 1) d += __shfl_xor(d, m, 64);
        if (ln == 0) s[b * LL + l] = d;
        float nM = fmaxf(Mw, d);
        float sc = __expf(Mw - nM);
        float e = __expf(d - nM);
        Sw = Sw * sc + e;
        Vw.x = Vw.x * sc + e * v.x;
        Vw.y = Vw.y * sc + e * v.y;
        Vw.z = Vw.z * sc + e * v.z;
        Vw.w = Vw.w * sc + e * v.w;
        Mw = nM;
    }
    __shared__ float sM4[4], sS4[4];
    __shared__ float sV[4][KK];
    sV[w][ln * 4 + 0] = Vw.x;
    sV[w][ln * 4 + 1] = Vw.y;
    sV[w][ln * 4 + 2] = Vw.z;
    sV[w][ln * 4 + 3] = Vw.w;
    if (ln == 0) { sM4[w] = Mw; sS4[w] = Sw; }
    __syncthreads();
    int k = tid;
    float M = fmaxf(fmaxf(sM4[0], sM4[1]), fmaxf(sM4[2], sM4[3]));
    float e0 = __expf(sM4[0] - M), e1 = __expf(sM4[1] - M);
    float e2 = __expf(sM4[2] - M), e3 = __expf(sM4[3] - M);
    float S = e0 * sS4[0] + e1 * sS4[1] + e2 * sS4[2] + e3 * sS4[3];
    float V = e0 * sV[0][k] + e1 * sV[1][k] + e2 * sV[2][k] + e3 * sV[3][k];
    partV[((size_t)(b * NC + c)) * KK + k] = V;
    if (tid == 0) {
        partM[b * NC + c] = M;
        partS[b * NC + c] = S;
    }
}

// ---------------- BG=2 fused writer (blocks 0..255) + reader t+1 (blocks 256..511) ----
// writer block (bg, jg): softmax-reduce for 2 batches, 64 gate-cols, 4-way k-split
// over 768 rows: [hr(256)|m_rt(256)]@Wf + hw@wWh, + bf.  shin: [b][768].
__global__ __launch_bounds__(256) void k_wrf(
    const float* __restrict__ partM, const float* __restrict__ partS,
    const float* __restrict__ partV, const float* __restrict__ hr_cur,
    const float* __restrict__ Wf, const float* __restrict__ bf,
    const float* __restrict__ wWh,
    const float* __restrict__ hw_in, const float* __restrict__ cw_in,
    float* __restrict__ hw_out, float* __restrict__ cw_out,
    float* __restrict__ Mf, float* __restrict__ Sf, float* __restrict__ out, int t,
    const float* __restrict__ x, const float* __restrict__ rWx,
    const float* __restrict__ rWh, const float* __restrict__ rbv,
    const float* __restrict__ hr_in, const float* __restrict__ cr_in,
    float* __restrict__ hr_out, float* __restrict__ cr_out, int do_reader) {
    __shared__ float shin[1536];
    __shared__ float sred[512];
    __shared__ float sg[128];
    __shared__ float sMp[2 * NC], sSp[2 * NC], sEp[2 * NC];
    __shared__ float sMS[2], sSS[2];
    int tid = threadIdx.x;
    if (blockIdx.x < 256) {
        int bg = blockIdx.x >> 4, jg = blockIdx.x & 15;
        if (tid < 64) {
            int bl = tid >> 5, c = tid & 31;
            sMp[tid] = partM[(bg * 2 + bl) * NC + c];
            sSp[tid] = partS[(bg * 2 + bl) * NC + c];
        }
        __syncthreads();
        if (tid < 2) {
            float M = -INFINITY;
#pragma unroll
            for (int c = 0; c < NC; c++) M = fmaxf(M, sMp[tid * NC + c]);
            sMS[tid] = M;
        }
        __syncthreads();
        if (tid < 64) sEp[tid] = __expf(sMp[tid] - sMS[tid >> 5]);
        __syncthreads();
        if (tid < 2) {
            float S = 0.f;
#pragma unroll
            for (int c = 0; c < NC; c++) S += sEp[tid * NC + c] * sSp[tid * NC + c];
            sSS[tid] = S;
            if (jg == 0) { Mf[bg * 2 + tid] = sMS[tid]; Sf[bg * 2 + tid] = S; }
        }
        __syncthreads();
#pragma unroll
        for (int b = 0; b < 2; b++) {
            int bglob = bg * 2 + b;
            float V = 0.f;
            for (int c = 0; c < NC; c++)
                V += sEp[b * NC + c] * partV[((size_t)(bglob * NC + c)) * KK + tid];
            shin[b * 768 + KK + tid] = V / sSS[b];
            shin[b * 768 + tid] = hr_cur[bglob * KK + tid];
            shin[b * 768 + N2K + tid] = hw_in[bglob * KK + tid];
        }
        __syncthreads();
        int c64 = tid & 63, ks = tid >> 6;
        int g = c64 >> 4, jq = c64 & 15;
        int col = g * KK + jg * 16 + jq;
        float binit = (ks == 0) ? bf[col] : 0.f;
        float acc0 = binit, acc1 = binit;
        int k0 = ks * 192, k1 = k0 + 192;
        int kb = k1 < N2K ? k1 : N2K;
        for (int k = k0; k < kb; k += 4) {
            float w0 = Wf[(size_t)(k + 0) * N4K + col];
            float w1 = Wf[(size_t)(k + 1) * N4K + col];
            float w2 = Wf[(size_t)(k + 2) * N4K + col];
            float w3 = Wf[(size_t)(k + 3) * N4K + col];
            float4 va = *(const float4*)&shin[k];
            float4 vb = *(const float4*)&shin[768 + k];
            acc0 += w0 * va.x + w1 * va.y + w2 * va.z + w3 * va.w;
            acc1 += w0 * vb.x + w1 * vb.y + w2 * vb.z + w3 * vb.w;
        }
        for (int k = (k0 > N2K ? k0 : N2K); k < k1; k += 4) {
            float w0 = wWh[(size_t)(k - N2K + 0) * N4K + col];
            float w1 = wWh[(size_t)(k - N2K + 1) * N4K + col];
            float w2 = wWh[(size_t)(k - N2K + 2) * N4K + col];
            float w3 = wWh[(size_t)(k - N2K + 3) * N4K + col];
            float4 va = *(const float4*)&shin[k];
            float4 vb = *(const float4*)&shin[768 + k];
            acc0 += w0 * va.x + w1 * va.y + w2 * va.z + w3 * va.w;
            acc1 += w0 * vb.x + w1 * vb.y + w2 * vb.z + w3 * vb.w;
        }
        sred[(ks * 64 + c64) * 2 + 0] = acc0;
        sred[(ks * 64 + c64) * 2 + 1] = acc1;
        __syncthreads();
        if (tid < 128) {
            int cc = tid >> 1, b = tid & 1;
            sg[tid] = sred[(0 * 64 + cc) * 2 + b] + sred[(1 * 64 + cc) * 2 + b] +
                      sred[(2 * 64 + cc) * 2 + b] + sred[(3 * 64 + cc) * 2 + b];
        }
        __syncthreads();
        if (tid < 32) {
            int jl = tid >> 1, b = tid & 1;
            int bglob = bg * 2 + b;
            int j = jg * 16 + jl;
            float gi = sg[(0 * 16 + jl) * 2 + b], gf = sg[(1 * 16 + jl) * 2 + b];
            float gG = sg[(2 * 16 + jl) * 2 + b], go = sg[(3 * 16 + jl) * 2 + b];
            float cn = sigf(gf) * cw_in[bglob * KK + j] + sigf(gi) * tanhf(gG);
            float hn = sigf(go) * tanhf(cn);
            cw_out[bglob * KK + j] = cn;
            hw_out[bglob * KK + j] = hn;
            out[((size_t)bglob * LL + t) * KK + j] = hn;
        }
    } else if (do_reader) {
        int r2 = blockIdx.x - 256;
        reader2(r2 >> 4, r2 & 15, tid, t + 1, x, rWx, rWh, rbv,
                hr_in, cr_in, hr_out, cr_out, shin, sred, sg);
    }
}

// ---------------- host ----------------
extern "C" void kernel_launch(void* const* d_in, const int* in_sizes, int n_in,
                              void* d_out, int out_size, void* d_ws, size_t ws_size,
                              hipStream_t stream) {
    const float* x   = (const float*)d_in[0];
    const float* rWx = (const float*)d_in[1];
    const float* rWh = (const float*)d_in[2];
    const float* rb  = (const float*)d_in[3];
    const float* wWx = (const float*)d_in[4];
    const float* wWh = (const float*)d_in[5];
    const float* wb  = (const float*)d_in[6];
    const float* cW  = (const float*)d_in[7];
    const float* cb  = (const float*)d_in[8];
    float* out = (float*)d_out;

    float* ws = (float*)d_ws;
    const size_t MEM = (size_t)Bb * LL * KK;  // 8388608
    float* mem = ws;
    float* states = ws + MEM;                 // 8 state buffers, contiguous
    float* hr[2] = {states + 0 * Bb * KK, states + 1 * Bb * KK};
    float* cr[2] = {states + 2 * Bb * KK, states + 3 * Bb * KK};
    float* hw[2] = {states + 4 * Bb * KK, states + 5 * Bb * KK};
    float* cw[2] = {states + 6 * Bb * KK, states + 7 * Bb * KK};
    float* s     = states + 8 * Bb * KK;              // B*L
    float* partM = s + (size_t)Bb * LL;               // B*NC
    float* partS = partM + Bb * NC;                   // B*NC
    float* partV = partS + Bb * NC;                   // B*NC*K
    float* Mf    = partV + (size_t)Bb * NC * KK;      // B
    float* Sf    = Mf + Bb;                           // B
    float* Wf    = Sf + Bb;                           // 512*1024
    float* bf    = Wf + (size_t)N2K * N4K;            // 1024

    k_init<<<4096, 256, 0, stream>>>(x, mem, states);
    k_pre<<<516, 256, 0, stream>>>(cW, cb, wWx, wb, Wf, bf);
    k_rd<<<256, 256, 0, stream>>>(x, rWx, rWh, rb, hr[0], cr[0], hr[1], cr[1], 0);

    for (int t = 0; t < LL; t++) {
        int pi = t & 1;
        int po = (t + 1) & 1;
        k_attn<<<dim3(NC, Bb), 256, 0, stream>>>(mem, hr[po], s, partM, partS, partV,
                                                 hw[pi], Mf, Sf, t > 0 ? 1 : 0);
        k_wrf<<<512, 256, 0, stream>>>(partM, partS, partV, hr[po], Wf, bf, wWh,
                                       hw[pi], cw[pi], hw[po], cw[po], Mf, Sf, out, t,
                                       x, rWx, rWh, rb, hr[po], cr[po], hr[pi], cr[pi],
                                       (t + 1 < LL) ? 1 : 0);
    }
}